// Round 18
// baseline (230.879 us; speedup 1.0000x reference)
//
#include <hip/hip_runtime.h>
#include <cstdint>

#define B_SZ   512
#define IN_SZ  3072
#define HID    2048
#define OUT_SZ 512
#define T_STEPS 10
#define NELEM  (512u*3072u)
#define KW     96                    // in_bits words per row
#define BITS_T_STRIDE (512u*96u)
#define M_ALL  (T_STEPS * B_SZ)
#define SCALE_UP   16384.0f          // 2^14 (exact)
#define SCALE_DN   6.103515625e-05f  // 2^-14 (exact)

typedef __attribute__((ext_vector_type(8))) _Float16 half8;   // 8 f16
typedef __attribute__((ext_vector_type(4))) float f32x4;
typedef __attribute__((ext_vector_type(16))) float f32x16;
typedef __attribute__((ext_vector_type(4))) unsigned int u32x4;

struct Keys { uint32_t k[2*T_STEPS]; };

__host__ __device__ inline void threefry2x32(uint32_t k0, uint32_t k1,
                                             uint32_t x0, uint32_t x1,
                                             uint32_t& y0, uint32_t& y1) {
  const uint32_t ks2 = k0 ^ k1 ^ 0x1BD11BDAu;
#define TF_R(r) { x0 += x1; x1 = (x1 << (r)) | (x1 >> (32-(r))); x1 ^= x0; }
  x0 += k0; x1 += k1;
  TF_R(13) TF_R(15) TF_R(26) TF_R(6)   x0 += k1;  x1 += ks2 + 1u;
  TF_R(17) TF_R(29) TF_R(16) TF_R(24)  x0 += ks2; x1 += k0  + 2u;
  TF_R(13) TF_R(15) TF_R(26) TF_R(6)   x0 += k0;  x1 += k1  + 3u;
  TF_R(17) TF_R(29) TF_R(16) TF_R(24)  x0 += k1;  x1 += ks2 + 4u;
  TF_R(13) TF_R(15) TF_R(26) TF_R(6)   x0 += ks2; x1 += k0  + 5u;
#undef TF_R
  y0 = x0; y1 = x1;
}

// ---------------- 2-way f16 split (pre-scaled by 2^14) ---------------------
__device__ __forceinline__ void split2x8h(const float* __restrict__ src,
                                          half8& hv, half8& mv) {
  float w8[8];
  *(f32x4*)&w8[0] = *(const f32x4*)&src[0];
  *(f32x4*)&w8[4] = *(const f32x4*)&src[4];
  union { _Float16 f[8]; half8 v; } h8, m8;
#pragma unroll
  for (int j = 0; j < 8; ++j) {
    float ws = w8[j] * SCALE_UP;           // exact (power of 2)
    _Float16 h = (_Float16)ws;             // RNE
    float r1 = ws - (float)h;              // exact
    _Float16 m = (_Float16)r1;             // RNE
    h8.f[j] = h; m8.f[j] = m;
  }
  hv = h8.v; mv = m8.v;
}

// ---------------- bit byte -> 8 f16 {0,1} ----------------------------------
__device__ __forceinline__ half8 expand8h(uint32_t b) {
  union { uint32_t u[4]; half8 v; } r;
#pragma unroll
  for (int j = 0; j < 4; ++j) {
    uint32_t x = b >> (2*j);
    r.u[j] = ((x & 1u) | ((x & 2u) << 15)) * 0x3C00u;  // f16 1.0 per set bit
  }
  return r.v;
}

// ---------------- fused prep: split32(Win) + split16(Wout) + spikegen ------
__global__ __launch_bounds__(256) void prep_kernel(
    const float* __restrict__ x, const float* __restrict__ Win,
    const float* __restrict__ Wout,
    ushort* __restrict__ Wfrag, ushort* __restrict__ Ofrag,
    uint32_t* __restrict__ pre_bits, Keys keys) {
  int blk = blockIdx.x;
  int tid = threadIdx.x;
  if (blk < 3072) {
    // 32-col fragment layout: out[nt32][ks16][2][512]  (verified r17)
    int bx = blk % 48, nt = blk / 48;
    int col = tid & 31;
    int cell = tid >> 5;
    int ks = bx * 4 + (cell >> 1);
    int kh = cell & 1;
    half8 hv, mv;
    split2x8h(&Win[(size_t)(nt * 32 + col) * IN_SZ + ks * 16 + kh * 8],
              hv, mv);
    size_t base =
        ((size_t)nt * (IN_SZ / 16) + ks) * 1024 + (kh * 32 + col) * 8;
    *(half8*)&Wfrag[base]       = hv;
    *(half8*)&Wfrag[base + 512] = mv;
  } else if (blk < 3584) {
    // 16-col fragment layout: out[nt16][ks32][2][512]  (verified r17)
    int q = blk - 3072;
    int bx = q % 16, nt = q / 16;
    int ks = bx * 4 + (tid >> 6);
    int kb = (tid >> 4) & 3, c = tid & 15;
    half8 hv, mv;
    split2x8h(&Wout[(size_t)(nt * 16 + c) * HID + ks * 32 + kb * 8], hv, mv);
    size_t base =
        ((size_t)nt * (HID / 32) + ks) * 1024 + (kb * 16 + c) * 8;
    *(half8*)&Ofrag[base]       = hv;
    *(half8*)&Ofrag[base + 512] = mv;
  } else {
    // spike generation (verified rounds 1/3-17)
    uint32_t m = (uint32_t)(blk - 3584) * 256u + tid;
    uint32_t b = m / IN_SZ;
    uint32_t j = m - b * IN_SZ;
    float xv = x[m];
    float p = (float)(1.0 / (1.0 + exp(-(double)xv)));
    uint32_t lane = tid & 63u;
    uint32_t wbase = b * KW + (j >> 5);
#pragma unroll
    for (int t = 0; t < T_STEPS; ++t) {
      uint32_t y0, y1;
      threefry2x32(keys.k[2*t], keys.k[2*t+1], 0u, m, y0, y1);
      uint32_t bits = y0 ^ y1;
      float u = __uint_as_float((bits >> 9) | 0x3f800000u) - 1.0f;
      unsigned long long mask = __ballot(u < p);
      if (lane == 0u) {
        *reinterpret_cast<unsigned long long*>(
            &pre_bits[(uint32_t)t * BITS_T_STRIDE + wbase]) = mask;
      }
    }
  }
}

#define MFMAH(a, b, c)   __builtin_amdgcn_mfma_f32_16x16x32_f16((a), (b), (c), 0, 0, 0)
#define MFMAH32(a, b, c) __builtin_amdgcn_mfma_f32_32x32x16_f16((a), (b), (c), 0, 0, 0)

// ---------------- hidden GEMM: 2xf16, BM=64, 5 blocks/CU -------------------
// 256 thr (4 waves 1m x 4n), tile 64m x 128n; wave = 64m x 32n (F=2).
// grid 1280 = 8 XCD x 2 xb x 80 mb, panel-ordered (all mb of panel0 first).
// Per-XCD B working set = 2 x 1.57 MB f16 panels = 3.15 MB < 4 MB L2 ->
// the 80 m-passes re-read from L2, not HBM (fixes R14's failure mode).
// Staged-A LDS dbuf (16 KB) + 2-deep B pipeline. FP order per (m,n)
// identical to R17 -> H bit-identical.
__global__ __launch_bounds__(256) void gemm_hidden(
    const ushort* __restrict__ Wfrag,       // [64 nt][192 ks][2][512]
    const uint32_t* __restrict__ in_bits,   // [5120][96]
    float* __restrict__ H) {                // [5120][2048]
  __shared__ ushort A_lds[2][4096];         // [8 j][2 f][32 row][8 e] x2 =16KB
  int lin = blockIdx.x;
  int xcd = lin & 7, w = lin >> 3;          // w 0..159
  int xb  = xcd * 2 + (w / 80);             // panel-ordered
  int mb  = w % 80;                         // m-block (64 rows)
  int tid  = threadIdx.x;
  int wave = tid >> 6, lane = tid & 63;
  int col  = lane & 31, kh = lane >> 5;
  int nt = xb * 4 + wave;                   // 32-col group
  int m0 = mb * 64;
  const ushort* bp = Wfrag + (size_t)nt * (192 * 1024);

  // staging: thread owns byte-slots 2t,2t+1 (same row, same 32-bit word)
  int r = tid >> 2;
  int j0 = (tid & 3) * 2;
  const uint32_t* rowp = in_bits + (size_t)(m0 + r) * KW + (j0 >> 2);
  int sh0 = (j0 & 3) * 8, sh1 = sh0 + 8;
  int off0 = (j0 * 2 + (r >> 5)) * 256 + (r & 31) * 8;
  int off1 = ((j0 + 1) * 2 + (r >> 5)) * 256 + (r & 31) * 8;

  f32x16 acc[2];
#pragma unroll
  for (int f = 0; f < 2; ++f)
#pragma unroll
    for (int q = 0; q < 16; ++q) acc[f][q] = 0.f;

  uint32_t br;   // bits word for the chunk being staged

#define STAGE(buf)                                                            \
  {                                                                           \
    *(half8*)&A_lds[buf][off0] = expand8h((br >> sh0) & 0xFFu);               \
    *(half8*)&A_lds[buf][off1] = expand8h((br >> sh1) & 0xFFu);               \
  }

#define BURST(sidx)                                                           \
  {                                                                           \
    int g2 = kc * 4 + (sidx) + 2;                                             \
    if (g2 > 191) g2 = 191;                                                   \
    const ushort* bn = bp + (size_t)g2 * 1024 + lane * 8;                     \
    half8 Bn0 = *(const half8*)&bn[0];                                        \
    half8 Bn1 = *(const half8*)&bn[512];                                      \
    half8 A[2];                                                               \
    _Pragma("unroll")                                                         \
    for (int f = 0; f < 2; ++f)                                               \
      A[f] = *(const half8*)&A_lds[cur][(2*(sidx) + kh) * 512 + f * 256       \
                                        + col * 8];                           \
    __builtin_amdgcn_s_setprio(1);                                            \
    _Pragma("unroll")                                                         \
    for (int f = 0; f < 2; ++f) acc[f] = MFMAH32(A[f], Bc0, acc[f]);          \
    _Pragma("unroll")                                                         \
    for (int f = 0; f < 2; ++f) acc[f] = MFMAH32(A[f], Bc1, acc[f]);          \
    __builtin_amdgcn_s_setprio(0);                                            \
    Bc0 = Bd0; Bc1 = Bd1;                                                     \
    Bd0 = Bn0; Bd1 = Bn1;                                                     \
  }

  // prologue: stage chunk 0, prefetch bits chunk 1, preload B[g=0], B[g=1]
  br = rowp[0];
  STAGE(0)
  br = rowp[2];
  half8 Bc0, Bc1, Bd0, Bd1;
  {
    const ushort* bk = bp + lane * 8;
    Bc0 = *(const half8*)&bk[0];
    Bc1 = *(const half8*)&bk[512];
    const ushort* bd = bk + 1024;
    Bd0 = *(const half8*)&bd[0];
    Bd1 = *(const half8*)&bd[512];
  }
  __syncthreads();

  for (int kc = 0; kc < 48; ++kc) {
    int cur = kc & 1;
    BURST(0)
    if (kc + 1 < 48) STAGE(cur ^ 1)                  // under s=0's shadow
    if (kc + 2 < 48) br = rowp[(kc + 2) * 2];        // prefetch chunk kc+2
    BURST(1)
    BURST(2)
    BURST(3)
    __syncthreads();
  }
#undef BURST
#undef STAGE

  // C layout (verified m74/m101, rounds 8-17): col=lane&31,
  // row=(q&3)+8*(q>>2)+4*kh.  Unscale by 2^-14 (exact).
#pragma unroll
  for (int f = 0; f < 2; ++f)
#pragma unroll
    for (int q = 0; q < 16; ++q) {
      int m = m0 + f * 32 + (q & 3) + 8 * (q >> 2) + 4 * kh;
      H[(size_t)m * HID + nt * 32 + col] = acc[f][q] * SCALE_DN;
    }
}

// ---------------- LIF scan over t (the only sequential part) ---------------
__global__ __launch_bounds__(256) void lif_scan(
    const float* __restrict__ H,           // [5120][2048]
    uint8_t* __restrict__ spk) {           // [T][512][256] bit-packed along n
  int idx  = blockIdx.x * 256 + threadIdx.x;   // 0 .. 512*2048-1
  int b = idx >> 11, n = idx & 2047;
  int lane = threadIdx.x & 63;
  size_t spk_off = (size_t)b * 256 + (size_t)((n >> 3) & ~7);
  float v = 0.f;
#pragma unroll
  for (int t = 0; t < T_STEPS; ++t) {
    float h = H[(size_t)(t * B_SZ + b) * HID + n];
    bool fire;
    {
#pragma clang fp contract(off)
      float vd = v * 0.3f;
      float vn = vd + h;
      fire = (vn >= 1.0f);
      v = fire ? 0.0f : vn;
    }
    unsigned long long mask = __ballot(fire);
    if (lane == 0)
      *(unsigned long long*)&spk[(size_t)t * (512*256) + spk_off] = mask;
  }
}

// ---------------- output layer, XCD-swizzled + B/aw pipelined, 2xf16 -------
__global__ __launch_bounds__(256) void out_mfma(
    const ushort* __restrict__ Ofrag,       // [32][64][2][512]
    const uint8_t* __restrict__ spk,        // [T][512][256]
    const float* __restrict__ bout,
    float* __restrict__ s) {                // [512][512], pre-zeroed
  int lin = blockIdx.x;
  int x = lin & 7;
  int r0 = lin >> 3;
  int y = r0 & 7;
  int t = r0 >> 3;
  int tid = threadIdx.x;
  int wave = tid >> 6, lane = tid & 63;
  int col  = lane & 15, kb = lane >> 4;
  int nt = x * 4 + wave;
  int m0 = y * 64;
  const ushort* bp = Ofrag + (size_t)nt * (64 * 1024);
  const uint8_t* st = spk + (size_t)t * (512*256);

  f32x4 acc[4] = {{0.f,0.f,0.f,0.f},{0.f,0.f,0.f,0.f},
                  {0.f,0.f,0.f,0.f},{0.f,0.f,0.f,0.f}};

  u32x4 aw[4], awn[4];
#pragma unroll
  for (int f = 0; f < 4; ++f)
    aw[f] = *(const u32x4*)&st[(size_t)(m0 + f*16 + col) * 256];
  half8 Bc0, Bc1;
  {
    const ushort* bk = bp + lane * 8;
    Bc0 = *(const half8*)&bk[0];
    Bc1 = *(const half8*)&bk[512];
  }

  for (int kc4 = 0; kc4 < 16; ++kc4) {      // K = 2048 = 16 * 4 * 32
    int nk4 = (kc4 + 1 < 16) ? kc4 + 1 : 15;
#pragma unroll
    for (int f = 0; f < 4; ++f)
      awn[f] = *(const u32x4*)&st[(size_t)(m0 + f*16 + col) * 256 + nk4*16];
#pragma unroll
    for (int sv = 0; sv < 4; ++sv) {
      int g1 = kc4 * 4 + sv + 1;
      if (g1 > 63) g1 = 63;
      const ushort* bn = bp + (size_t)g1 * 1024 + lane * 8;
      half8 Bn0 = *(const half8*)&bn[0];
      half8 Bn1 = *(const half8*)&bn[512];
      half8 A[4];
#pragma unroll
      for (int f = 0; f < 4; ++f)
        A[f] = expand8h((aw[f][sv] >> (kb*8)) & 0xFFu);
      __builtin_amdgcn_s_setprio(1);
#pragma unroll
      for (int f = 0; f < 4; ++f) acc[f] = MFMAH(A[f], Bc0, acc[f]);
#pragma unroll
      for (int f = 0; f < 4; ++f) acc[f] = MFMAH(A[f], Bc1, acc[f]);
      __builtin_amdgcn_s_setprio(0);
      Bc0 = Bn0; Bc1 = Bn1;
    }
#pragma unroll
    for (int f = 0; f < 4; ++f) aw[f] = awn[f];
  }
  float bo = bout[nt*16 + col];
#pragma unroll
  for (int f = 0; f < 4; ++f) {
#pragma unroll
    for (int r = 0; r < 4; ++r) {
      float out = acc[f][r] * SCALE_DN + bo;
      if (out > 0.0f) {
        int b = m0 + f*16 + kb*4 + r;
        atomicAdd(&s[(size_t)b * OUT_SZ + nt*16 + col], 1.0f);
      }
    }
  }
}

// ---------------------------------------------------------------------------
extern "C" void kernel_launch(void* const* d_in, const int* in_sizes, int n_in,
                              void* d_out, int out_size, void* d_ws, size_t ws_size,
                              hipStream_t stream) {
  const float* x    = (const float*)d_in[0];
  const float* Win  = (const float*)d_in[1];   // [2048][3072]
  const float* Wout = (const float*)d_in[2];   // [512][2048]
  const float* bout = (const float*)d_in[3];
  float* s = (float*)d_out;                    // [512][512]

  char* ws = (char*)d_ws;
  ushort*   Wfrag   = (ushort*)(ws + 0);           // 64*192*1024*2 = 25165824
  ushort*   Ofrag   = (ushort*)(ws + 25165824);    // 32*64*1024*2  = 4194304
  uint32_t* in_bits = (uint32_t*)(ws + 29360128);  // 10*512*96*4   = 1966080
  uint8_t*  spk     = (uint8_t*)(ws + 31326208);   // 10*512*256    = 1310720
  float*    H       = (float*)(ws + 32636928);     // 5120*2048*4   = 41943040

  Keys hk;
  for (int t = 0; t < T_STEPS; ++t) {
    uint32_t y0, y1;
    threefry2x32(0u, 42u, 0u, (uint32_t)t, y0, y1);
    hk.k[2*t] = y0; hk.k[2*t+1] = y1;
  }

  (void)hipMemsetAsync(d_out, 0, (size_t)OUT_SZ * B_SZ * sizeof(float), stream);
  hipLaunchKernelGGL(prep_kernel, dim3(3072 + 512 + NELEM/256), dim3(256), 0,
                     stream, x, Win, Wout, Wfrag, Ofrag, in_bits, hk);
  hipLaunchKernelGGL(gemm_hidden, dim3(1280), dim3(256), 0, stream,
                     Wfrag, in_bits, H);
  hipLaunchKernelGGL(lif_scan, dim3((B_SZ*HID)/256), dim3(256), 0, stream,
                     H, spk);
  hipLaunchKernelGGL(out_mfma, dim3(8 * 8 * T_STEPS), dim3(256), 0, stream,
                     Ofrag, spk, bout, s);
}

// Round 19
// 214.116 us; speedup vs baseline: 1.0783x; 1.0783x over previous
//
#include <hip/hip_runtime.h>
#include <cstdint>

#define B_SZ   512
#define IN_SZ  3072
#define HID    2048
#define OUT_SZ 512
#define T_STEPS 10
#define NELEM  (512u*3072u)
#define KW     96                    // in_bits words per row
#define BITS_T_STRIDE (512u*96u)
#define M_ALL  (T_STEPS * B_SZ)
#define SCALE_UP   16384.0f          // 2^14 (exact)
#define SCALE_DN   6.103515625e-05f  // 2^-14 (exact)

typedef __attribute__((ext_vector_type(8))) _Float16 half8;   // 8 f16
typedef __attribute__((ext_vector_type(4))) float f32x4;
typedef __attribute__((ext_vector_type(16))) float f32x16;
typedef __attribute__((ext_vector_type(4))) unsigned int u32x4;

struct Keys { uint32_t k[2*T_STEPS]; };

__host__ __device__ inline void threefry2x32(uint32_t k0, uint32_t k1,
                                             uint32_t x0, uint32_t x1,
                                             uint32_t& y0, uint32_t& y1) {
  const uint32_t ks2 = k0 ^ k1 ^ 0x1BD11BDAu;
#define TF_R(r) { x0 += x1; x1 = (x1 << (r)) | (x1 >> (32-(r))); x1 ^= x0; }
  x0 += k0; x1 += k1;
  TF_R(13) TF_R(15) TF_R(26) TF_R(6)   x0 += k1;  x1 += ks2 + 1u;
  TF_R(17) TF_R(29) TF_R(16) TF_R(24)  x0 += ks2; x1 += k0  + 2u;
  TF_R(13) TF_R(15) TF_R(26) TF_R(6)   x0 += k0;  x1 += k1  + 3u;
  TF_R(17) TF_R(29) TF_R(16) TF_R(24)  x0 += k1;  x1 += ks2 + 4u;
  TF_R(13) TF_R(15) TF_R(26) TF_R(6)   x0 += ks2; x1 += k0  + 5u;
#undef TF_R
  y0 = x0; y1 = x1;
}

// ---------------- 2-way f16 split (pre-scaled by 2^14) ---------------------
// w*2^14 = hi + mid + r2, |r2| <= 2^-24 * |w*2^14|; r2 dropped.
__device__ __forceinline__ void split2x8h(const float* __restrict__ src,
                                          half8& hv, half8& mv) {
  float w8[8];
  *(f32x4*)&w8[0] = *(const f32x4*)&src[0];
  *(f32x4*)&w8[4] = *(const f32x4*)&src[4];
  union { _Float16 f[8]; half8 v; } h8, m8;
#pragma unroll
  for (int j = 0; j < 8; ++j) {
    float ws = w8[j] * SCALE_UP;           // exact (power of 2)
    _Float16 h = (_Float16)ws;             // RNE via v_cvt_f16_f32
    float r1 = ws - (float)h;              // exact
    _Float16 m = (_Float16)r1;             // RNE
    h8.f[j] = h; m8.f[j] = m;
  }
  hv = h8.v; mv = m8.v;
}

// ---------------- bit byte -> 8 f16 {0,1} ----------------------------------
__device__ __forceinline__ half8 expand8h(uint32_t b) {
  union { uint32_t u[4]; half8 v; } r;
#pragma unroll
  for (int j = 0; j < 4; ++j) {
    uint32_t x = b >> (2*j);
    r.u[j] = ((x & 1u) | ((x & 2u) << 15)) * 0x3C00u;  // f16 1.0 per set bit
  }
  return r.v;
}

// ---------------- fused prep: split32(Win) + split16(Wout) + spikegen ------
// blocks [0,3072): Win split; [3072,3584): Wout split; [3584,9728): spikegen
__global__ __launch_bounds__(256) void prep_kernel(
    const float* __restrict__ x, const float* __restrict__ Win,
    const float* __restrict__ Wout,
    ushort* __restrict__ Wfrag, ushort* __restrict__ Ofrag,
    uint32_t* __restrict__ pre_bits, Keys keys) {
  int blk = blockIdx.x;
  int tid = threadIdx.x;
  if (blk < 3072) {
    // 32-col fragment layout: out[nt32][ks16][2][512],
    // entry (kh*32+c)*8+e = W[nt*32+c][ks*16+kh*8+e]  (verified r17)
    int bx = blk % 48, nt = blk / 48;
    int col = tid & 31;
    int cell = tid >> 5;
    int ks = bx * 4 + (cell >> 1);
    int kh = cell & 1;
    half8 hv, mv;
    split2x8h(&Win[(size_t)(nt * 32 + col) * IN_SZ + ks * 16 + kh * 8],
              hv, mv);
    size_t base =
        ((size_t)nt * (IN_SZ / 16) + ks) * 1024 + (kh * 32 + col) * 8;
    *(half8*)&Wfrag[base]       = hv;
    *(half8*)&Wfrag[base + 512] = mv;
  } else if (blk < 3584) {
    // 16-col fragment layout: out[nt16][ks32][2][512]  (verified r17)
    int q = blk - 3072;
    int bx = q % 16, nt = q / 16;
    int ks = bx * 4 + (tid >> 6);
    int kb = (tid >> 4) & 3, c = tid & 15;
    half8 hv, mv;
    split2x8h(&Wout[(size_t)(nt * 16 + c) * HID + ks * 32 + kb * 8], hv, mv);
    size_t base =
        ((size_t)nt * (HID / 32) + ks) * 1024 + (kb * 16 + c) * 8;
    *(half8*)&Ofrag[base]       = hv;
    *(half8*)&Ofrag[base + 512] = mv;
  } else {
    // spike generation (verified rounds 1/3-17)
    uint32_t m = (uint32_t)(blk - 3584) * 256u + tid;
    uint32_t b = m / IN_SZ;
    uint32_t j = m - b * IN_SZ;
    float xv = x[m];
    float p = (float)(1.0 / (1.0 + exp(-(double)xv)));
    uint32_t lane = tid & 63u;
    uint32_t wbase = b * KW + (j >> 5);
#pragma unroll
    for (int t = 0; t < T_STEPS; ++t) {
      uint32_t y0, y1;
      threefry2x32(keys.k[2*t], keys.k[2*t+1], 0u, m, y0, y1);
      uint32_t bits = y0 ^ y1;
      float u = __uint_as_float((bits >> 9) | 0x3f800000u) - 1.0f;
      unsigned long long mask = __ballot(u < p);
      if (lane == 0u) {
        *reinterpret_cast<unsigned long long*>(
            &pre_bits[(uint32_t)t * BITS_T_STRIDE + wbase]) = mask;
      }
    }
  }
}

#define MFMAH(a, b, c)   __builtin_amdgcn_mfma_f32_16x16x32_f16((a), (b), (c), 0, 0, 0)
#define MFMAH32(a, b, c) __builtin_amdgcn_mfma_f32_32x32x16_f16((a), (b), (c), 0, 0, 0)

// ---------------- hidden GEMM: R15 structure, 2xf16 splits (best, r17) -----
// 256 thr (4 waves 1m x 4n), tile 160m x 128n; wave = 160m x 32n (F=5).
// grid 512 = 8 XCD x 2 xb x 32 mb -> 2 blocks/CU; LDS 40 KB; panel-ordered.
// Staged-A LDS dbuf + 2-deep B pipeline. Epilogue unscales by 2^-14 (exact).
__global__ __launch_bounds__(256) void gemm_hidden(
    const ushort* __restrict__ Wfrag,       // [64 nt][192 ks][2][512]
    const uint32_t* __restrict__ in_bits,   // [5120][96]
    float* __restrict__ H) {                // [5120][2048]
  __shared__ ushort A_lds[2][10240];        // [8 j][5 f][32 row][8 e] x2 = 40KB
  int lin = blockIdx.x;
  int xcd = lin & 7, w = lin >> 3;          // w 0..63
  int xb  = xcd * 2 + (w >> 5);             // n-panel: all mb of panel0 first
  int mb  = w & 31;                         // m-block (160 rows), 0..31
  int tid  = threadIdx.x;
  int wave = tid >> 6, lane = tid & 63;
  int col  = lane & 31, kh = lane >> 5;
  int nt = xb * 4 + wave;                   // 32-col group
  int m0 = mb * 160;
  const ushort* bp = Wfrag + (size_t)nt * (192 * 1024);

  // staging: byte-slot s = r*8 + j; thread owns slots 5t..5t+4 (r11-17)
  int s0 = tid * 5;
  int r0 = s0 >> 3, r1 = (s0 + 4) >> 3;
  const uint32_t* rowp0 = in_bits + (size_t)(m0 + r0) * KW;
  const uint32_t* rowp1 = in_bits + (size_t)(m0 + r1) * KW;
  int hi_[5], ws_[5], sh_[5], off_[5];
#pragma unroll
  for (int p = 0; p < 5; ++p) {
    int s = s0 + p, r = s >> 3, j = s & 7;
    hi_[p]  = (r != r0);
    ws_[p]  = (j >> 2) & 1;
    sh_[p]  = (j & 3) * 8;
    off_[p] = (j * 5 + (r >> 5)) * 256 + (r & 31) * 8;
  }

  f32x16 acc[5];
#pragma unroll
  for (int f = 0; f < 5; ++f)
#pragma unroll
    for (int r = 0; r < 16; ++r) acc[f][r] = 0.f;

  uint2 br0, br1;   // bits words (2 per row) for the chunk being staged

#define STAGE(buf)                                                            \
  {                                                                           \
    _Pragma("unroll")                                                         \
    for (int p = 0; p < 5; ++p) {                                             \
      uint32_t wv = hi_[p] ? (ws_[p] ? br1.y : br1.x)                         \
                           : (ws_[p] ? br0.y : br0.x);                        \
      *(half8*)&A_lds[buf][off_[p]] = expand8h((wv >> sh_[p]) & 0xFFu);       \
    }                                                                         \
  }

#define BURST(sidx)                                                           \
  {                                                                           \
    int g2 = kc * 4 + (sidx) + 2;                                             \
    if (g2 > 191) g2 = 191;                                                   \
    const ushort* bn = bp + (size_t)g2 * 1024 + lane * 8;                     \
    half8 Bn0 = *(const half8*)&bn[0];                                        \
    half8 Bn1 = *(const half8*)&bn[512];                                      \
    half8 A[5];                                                               \
    _Pragma("unroll")                                                         \
    for (int f = 0; f < 5; ++f)                                               \
      A[f] = *(const half8*)&A_lds[cur][(sidx) * 2560 + aoff + f * 256];      \
    __builtin_amdgcn_s_setprio(1);                                            \
    _Pragma("unroll")                                                         \
    for (int f = 0; f < 5; ++f) acc[f] = MFMAH32(A[f], Bc0, acc[f]);          \
    _Pragma("unroll")                                                         \
    for (int f = 0; f < 5; ++f) acc[f] = MFMAH32(A[f], Bc1, acc[f]);          \
    __builtin_amdgcn_s_setprio(0);                                            \
    Bc0 = Bd0; Bc1 = Bd1;                                                     \
    Bd0 = Bn0; Bd1 = Bn1;                                                     \
  }

  // prologue: stage chunk 0, prefetch bits chunk 1, preload B[g=0], B[g=1]
  br0 = *(const uint2*)&rowp0[0];
  br1 = *(const uint2*)&rowp1[0];
  STAGE(0)
  br0 = *(const uint2*)&rowp0[2];
  br1 = *(const uint2*)&rowp1[2];
  half8 Bc0, Bc1, Bd0, Bd1;
  {
    const ushort* bk = bp + lane * 8;
    Bc0 = *(const half8*)&bk[0];
    Bc1 = *(const half8*)&bk[512];
    const ushort* bd = bk + 1024;
    Bd0 = *(const half8*)&bd[0];
    Bd1 = *(const half8*)&bd[512];
  }
  __syncthreads();

  int aoff = kh * 5 * 256 + col * 8;   // wave's A-frag base within a j-pair

  for (int kc = 0; kc < 48; ++kc) {
    int cur = kc & 1;
    BURST(0)
    if (kc + 1 < 48) STAGE(cur ^ 1)                  // under s=0's shadow
    if (kc + 2 < 48) {                               // prefetch chunk kc+2
      br0 = *(const uint2*)&rowp0[(kc + 2) * 2];
      br1 = *(const uint2*)&rowp1[(kc + 2) * 2];
    }
    BURST(1)
    BURST(2)
    BURST(3)
    __syncthreads();
  }
#undef BURST
#undef STAGE

  // C layout (verified m74/m101, rounds 8-17): col=lane&31,
  // row=(r&3)+8*(r>>2)+4*kh.  Unscale by 2^-14 (exact).
#pragma unroll
  for (int f = 0; f < 5; ++f)
#pragma unroll
    for (int r = 0; r < 16; ++r) {
      int m = m0 + f * 32 + (r & 3) + 8 * (r >> 2) + 4 * kh;
      H[(size_t)m * HID + nt * 32 + col] = acc[f][r] * SCALE_DN;
    }
}

// ---------------- LIF scan over t (the only sequential part) ---------------
__global__ __launch_bounds__(256) void lif_scan(
    const float* __restrict__ H,           // [5120][2048]
    uint8_t* __restrict__ spk) {           // [T][512][256] bit-packed along n
  int idx  = blockIdx.x * 256 + threadIdx.x;   // 0 .. 512*2048-1
  int b = idx >> 11, n = idx & 2047;
  int lane = threadIdx.x & 63;
  size_t spk_off = (size_t)b * 256 + (size_t)((n >> 3) & ~7);
  float v = 0.f;
#pragma unroll
  for (int t = 0; t < T_STEPS; ++t) {
    float h = H[(size_t)(t * B_SZ + b) * HID + n];
    bool fire;
    {
#pragma clang fp contract(off)
      float vd = v * 0.3f;
      float vn = vd + h;
      fire = (vn >= 1.0f);
      v = fire ? 0.0f : vn;
    }
    unsigned long long mask = __ballot(fire);
    if (lane == 0)
      *(unsigned long long*)&spk[(size_t)t * (512*256) + spk_off] = mask;
  }
}

// ---------------- output layer, XCD-swizzled + B/aw pipelined, 2xf16 -------
__global__ __launch_bounds__(256) void out_mfma(
    const ushort* __restrict__ Ofrag,       // [32][64][2][512]
    const uint8_t* __restrict__ spk,        // [T][512][256]
    const float* __restrict__ bout,
    float* __restrict__ s) {                // [512][512], pre-zeroed
  int lin = blockIdx.x;
  int x = lin & 7;
  int r0 = lin >> 3;
  int y = r0 & 7;
  int t = r0 >> 3;
  int tid = threadIdx.x;
  int wave = tid >> 6, lane = tid & 63;
  int col  = lane & 15, kb = lane >> 4;
  int nt = x * 4 + wave;
  int m0 = y * 64;
  const ushort* bp = Ofrag + (size_t)nt * (64 * 1024);
  const uint8_t* st = spk + (size_t)t * (512*256);

  f32x4 acc[4] = {{0.f,0.f,0.f,0.f},{0.f,0.f,0.f,0.f},
                  {0.f,0.f,0.f,0.f},{0.f,0.f,0.f,0.f}};

  // prologue: aw for kc4=0, B for g=0
  u32x4 aw[4], awn[4];
#pragma unroll
  for (int f = 0; f < 4; ++f)
    aw[f] = *(const u32x4*)&st[(size_t)(m0 + f*16 + col) * 256];
  half8 Bc0, Bc1;
  {
    const ushort* bk = bp + lane * 8;
    Bc0 = *(const half8*)&bk[0];
    Bc1 = *(const half8*)&bk[512];
  }

  for (int kc4 = 0; kc4 < 16; ++kc4) {      // K = 2048 = 16 * 4 * 32
    int nk4 = (kc4 + 1 < 16) ? kc4 + 1 : 15;
#pragma unroll
    for (int f = 0; f < 4; ++f)
      awn[f] = *(const u32x4*)&st[(size_t)(m0 + f*16 + col) * 256 + nk4*16];
#pragma unroll
    for (int sv = 0; sv < 4; ++sv) {
      int g1 = kc4 * 4 + sv + 1;
      if (g1 > 63) g1 = 63;
      const ushort* bn = bp + (size_t)g1 * 1024 + lane * 8;
      half8 Bn0 = *(const half8*)&bn[0];
      half8 Bn1 = *(const half8*)&bn[512];
      half8 A[4];
#pragma unroll
      for (int f = 0; f < 4; ++f)
        A[f] = expand8h((aw[f][sv] >> (kb*8)) & 0xFFu);
      __builtin_amdgcn_s_setprio(1);
#pragma unroll
      for (int f = 0; f < 4; ++f) acc[f] = MFMAH(A[f], Bc0, acc[f]);
#pragma unroll
      for (int f = 0; f < 4; ++f) acc[f] = MFMAH(A[f], Bc1, acc[f]);
      __builtin_amdgcn_s_setprio(0);
      Bc0 = Bn0; Bc1 = Bn1;
    }
#pragma unroll
    for (int f = 0; f < 4; ++f) aw[f] = awn[f];
  }
  float bo = bout[nt*16 + col];
#pragma unroll
  for (int f = 0; f < 4; ++f) {
#pragma unroll
    for (int r = 0; r < 4; ++r) {
      // acc*2^-14 exact; single rounding on +bo (same as unscaled path)
      float out = acc[f][r] * SCALE_DN + bo;
      if (out > 0.0f) {
        int b = m0 + f*16 + kb*4 + r;
        atomicAdd(&s[(size_t)b * OUT_SZ + nt*16 + col], 1.0f);
      }
    }
  }
}

// ---------------------------------------------------------------------------
extern "C" void kernel_launch(void* const* d_in, const int* in_sizes, int n_in,
                              void* d_out, int out_size, void* d_ws, size_t ws_size,
                              hipStream_t stream) {
  const float* x    = (const float*)d_in[0];
  const float* Win  = (const float*)d_in[1];   // [2048][3072]
  const float* Wout = (const float*)d_in[2];   // [512][2048]
  const float* bout = (const float*)d_in[3];
  float* s = (float*)d_out;                    // [512][512]

  char* ws = (char*)d_ws;
  ushort*   Wfrag   = (ushort*)(ws + 0);           // 64*192*1024*2 = 25165824
  ushort*   Ofrag   = (ushort*)(ws + 25165824);    // 32*64*1024*2  = 4194304
  uint32_t* in_bits = (uint32_t*)(ws + 29360128);  // 10*512*96*4   = 1966080
  uint8_t*  spk     = (uint8_t*)(ws + 31326208);   // 10*512*256    = 1310720
  float*    H       = (float*)(ws + 32636928);     // 5120*2048*4   = 41943040

  Keys hk;
  for (int t = 0; t < T_STEPS; ++t) {
    uint32_t y0, y1;
    threefry2x32(0u, 42u, 0u, (uint32_t)t, y0, y1);
    hk.k[2*t] = y0; hk.k[2*t+1] = y1;
  }

  (void)hipMemsetAsync(d_out, 0, (size_t)OUT_SZ * B_SZ * sizeof(float), stream);
  hipLaunchKernelGGL(prep_kernel, dim3(3072 + 512 + NELEM/256), dim3(256), 0,
                     stream, x, Win, Wout, Wfrag, Ofrag, in_bits, hk);
  hipLaunchKernelGGL(gemm_hidden, dim3(512), dim3(256), 0, stream,
                     Wfrag, in_bits, H);
  hipLaunchKernelGGL(lif_scan, dim3((B_SZ*HID)/256), dim3(256), 0, stream,
                     H, spk);
  hipLaunchKernelGGL(out_mfma, dim3(8 * 8 * T_STEPS), dim3(256), 0, stream,
                     Ofrag, spk, bout, s);
}

// Round 20
// 206.978 us; speedup vs baseline: 1.1155x; 1.0345x over previous
//
#include <hip/hip_runtime.h>
#include <cstdint>

#define B_SZ   512
#define IN_SZ  3072
#define HID    2048
#define OUT_SZ 512
#define T_STEPS 10
#define NELEM  (512u*3072u)
#define KW     96                    // in_bits words per row
#define M_ALL  (T_STEPS * B_SZ)
#define SCALE_UP   16384.0f          // 2^14 (exact)
#define SCALE_DN   6.103515625e-05f  // 2^-14 (exact)

typedef __attribute__((ext_vector_type(8))) _Float16 half8;   // 8 f16
typedef __attribute__((ext_vector_type(4))) float f32x4;
typedef __attribute__((ext_vector_type(16))) float f32x16;
typedef __attribute__((ext_vector_type(4))) unsigned int u32x4;

struct Keys { uint32_t k[2*T_STEPS]; };

__host__ __device__ inline void threefry2x32(uint32_t k0, uint32_t k1,
                                             uint32_t x0, uint32_t x1,
                                             uint32_t& y0, uint32_t& y1) {
  const uint32_t ks2 = k0 ^ k1 ^ 0x1BD11BDAu;
#define TF_R(r) { x0 += x1; x1 = (x1 << (r)) | (x1 >> (32-(r))); x1 ^= x0; }
  x0 += k0; x1 += k1;
  TF_R(13) TF_R(15) TF_R(26) TF_R(6)   x0 += k1;  x1 += ks2 + 1u;
  TF_R(17) TF_R(29) TF_R(16) TF_R(24)  x0 += ks2; x1 += k0  + 2u;
  TF_R(13) TF_R(15) TF_R(26) TF_R(6)   x0 += k0;  x1 += k1  + 3u;
  TF_R(17) TF_R(29) TF_R(16) TF_R(24)  x0 += k1;  x1 += ks2 + 4u;
  TF_R(13) TF_R(15) TF_R(26) TF_R(6)   x0 += ks2; x1 += k0  + 5u;
#undef TF_R
  y0 = x0; y1 = x1;
}

// ---------------- 2-way f16 split (pre-scaled by 2^14) ---------------------
__device__ __forceinline__ void split2x8h(const float* __restrict__ src,
                                          half8& hv, half8& mv) {
  float w8[8];
  *(f32x4*)&w8[0] = *(const f32x4*)&src[0];
  *(f32x4*)&w8[4] = *(const f32x4*)&src[4];
  union { _Float16 f[8]; half8 v; } h8, m8;
#pragma unroll
  for (int j = 0; j < 8; ++j) {
    float ws = w8[j] * SCALE_UP;           // exact (power of 2)
    _Float16 h = (_Float16)ws;             // RNE
    float r1 = ws - (float)h;              // exact
    _Float16 m = (_Float16)r1;             // RNE
    h8.f[j] = h; m8.f[j] = m;
  }
  hv = h8.v; mv = m8.v;
}

// ---------------- bit byte -> 8 f16 {0,1} ----------------------------------
__device__ __forceinline__ half8 expand8h(uint32_t b) {
  union { uint32_t u[4]; half8 v; } r;
#pragma unroll
  for (int j = 0; j < 4; ++j) {
    uint32_t x = b >> (2*j);
    r.u[j] = ((x & 1u) | ((x & 2u) << 15)) * 0x3C00u;  // f16 1.0 per set bit
  }
  return r.v;
}

// ---------------- fused prep: split32(Win) + split16(Wout) + spikegen ------
// in_bits rows are B-MAJOR: row = b*10 + t  (so gemm tiles own full t-seqs)
__global__ __launch_bounds__(256) void prep_kernel(
    const float* __restrict__ x, const float* __restrict__ Win,
    const float* __restrict__ Wout,
    ushort* __restrict__ Wfrag, ushort* __restrict__ Ofrag,
    uint32_t* __restrict__ pre_bits, Keys keys) {
  int blk = blockIdx.x;
  int tid = threadIdx.x;
  if (blk < 3072) {
    // 32-col fragment layout: out[nt32][ks16][2][512]  (verified r17/r19)
    int bx = blk % 48, nt = blk / 48;
    int col = tid & 31;
    int cell = tid >> 5;
    int ks = bx * 4 + (cell >> 1);
    int kh = cell & 1;
    half8 hv, mv;
    split2x8h(&Win[(size_t)(nt * 32 + col) * IN_SZ + ks * 16 + kh * 8],
              hv, mv);
    size_t base =
        ((size_t)nt * (IN_SZ / 16) + ks) * 1024 + (kh * 32 + col) * 8;
    *(half8*)&Wfrag[base]       = hv;
    *(half8*)&Wfrag[base + 512] = mv;
  } else if (blk < 3584) {
    // 16-col fragment layout: out[nt16][ks32][2][512]  (verified r17/r19)
    int q = blk - 3072;
    int bx = q % 16, nt = q / 16;
    int ks = bx * 4 + (tid >> 6);
    int kb = (tid >> 4) & 3, c = tid & 15;
    half8 hv, mv;
    split2x8h(&Wout[(size_t)(nt * 16 + c) * HID + ks * 32 + kb * 8], hv, mv);
    size_t base =
        ((size_t)nt * (HID / 32) + ks) * 1024 + (kb * 16 + c) * 8;
    *(half8*)&Ofrag[base]       = hv;
    *(half8*)&Ofrag[base + 512] = mv;
  } else {
    // spike generation (RNG verified rounds 1/3-19); row = b*10 + t
    uint32_t m = (uint32_t)(blk - 3584) * 256u + tid;
    uint32_t b = m / IN_SZ;
    uint32_t j = m - b * IN_SZ;
    float xv = x[m];
    float p = (float)(1.0 / (1.0 + exp(-(double)xv)));
    uint32_t lane = tid & 63u;
#pragma unroll
    for (int t = 0; t < T_STEPS; ++t) {
      uint32_t y0, y1;
      threefry2x32(keys.k[2*t], keys.k[2*t+1], 0u, m, y0, y1);
      uint32_t bits = y0 ^ y1;
      float u = __uint_as_float((bits >> 9) | 0x3f800000u) - 1.0f;
      unsigned long long mask = __ballot(u < p);
      if (lane == 0u) {
        *reinterpret_cast<unsigned long long*>(
            &pre_bits[(b * 10u + (uint32_t)t) * KW + (j >> 5)]) = mask;
      }
    }
  }
}

#define MFMAH(a, b, c)   __builtin_amdgcn_mfma_f32_16x16x32_f16((a), (b), (c), 0, 0, 0)
#define MFMAH32(a, b, c) __builtin_amdgcn_mfma_f32_32x32x16_f16((a), (b), (c), 0, 0, 0)

// ---------------- hidden GEMM + fused LIF scan (no H, no lif_scan) ---------
// R17/R19 main loop unchanged (256 thr, tile 160m x 128n, grid 512,
// panel-ordered, staged-A dbuf, 2-deep B pipeline). M is b-major:
// rows = 16 b's x 10 t. Epilogue: 2 column-half passes through 40 KB LDS;
// each wave LIF-scans 4 b's x 64 n's over t, packs fire bits via ballot.
__global__ __launch_bounds__(256) void gemm_hidden(
    const ushort* __restrict__ Wfrag,       // [64 nt][192 ks][2][512]
    const uint32_t* __restrict__ in_bits,   // [5120][96] rows b-major
    uint8_t* __restrict__ spk) {            // [T][512][256] bit-packed along n
  __shared__ ushort A_lds[2][10240];        // 40 KB (reused by epilogue)
  int lin = blockIdx.x;
  int xcd = lin & 7, w = lin >> 3;          // w 0..63
  int xb  = xcd * 2 + (w >> 5);             // n-panel: all mb of panel0 first
  int mb  = w & 31;                         // m-block (160 rows = 16 b's)
  int tid  = threadIdx.x;
  int wave = tid >> 6, lane = tid & 63;
  int col  = lane & 31, kh = lane >> 5;
  int nt = xb * 4 + wave;                   // 32-col group
  int m0 = mb * 160;
  const ushort* bp = Wfrag + (size_t)nt * (192 * 1024);

  // staging: byte-slot s = r*8 + j; thread owns slots 5t..5t+4 (r11-19)
  int s0 = tid * 5;
  int r0 = s0 >> 3, r1 = (s0 + 4) >> 3;
  const uint32_t* rowp0 = in_bits + (size_t)(m0 + r0) * KW;
  const uint32_t* rowp1 = in_bits + (size_t)(m0 + r1) * KW;
  int hi_[5], ws_[5], sh_[5], off_[5];
#pragma unroll
  for (int p = 0; p < 5; ++p) {
    int s = s0 + p, r = s >> 3, j = s & 7;
    hi_[p]  = (r != r0);
    ws_[p]  = (j >> 2) & 1;
    sh_[p]  = (j & 3) * 8;
    off_[p] = (j * 5 + (r >> 5)) * 256 + (r & 31) * 8;
  }

  f32x16 acc[5];
#pragma unroll
  for (int f = 0; f < 5; ++f)
#pragma unroll
    for (int r = 0; r < 16; ++r) acc[f][r] = 0.f;

  uint2 br0, br1;   // bits words (2 per row) for the chunk being staged

#define STAGE(buf)                                                            \
  {                                                                           \
    _Pragma("unroll")                                                         \
    for (int p = 0; p < 5; ++p) {                                             \
      uint32_t wv = hi_[p] ? (ws_[p] ? br1.y : br1.x)                         \
                           : (ws_[p] ? br0.y : br0.x);                        \
      *(half8*)&A_lds[buf][off_[p]] = expand8h((wv >> sh_[p]) & 0xFFu);       \
    }                                                                         \
  }

#define BURST(sidx)                                                           \
  {                                                                           \
    int g2 = kc * 4 + (sidx) + 2;                                             \
    if (g2 > 191) g2 = 191;                                                   \
    const ushort* bn = bp + (size_t)g2 * 1024 + lane * 8;                     \
    half8 Bn0 = *(const half8*)&bn[0];                                        \
    half8 Bn1 = *(const half8*)&bn[512];                                      \
    half8 A[5];                                                               \
    _Pragma("unroll")                                                         \
    for (int f = 0; f < 5; ++f)                                               \
      A[f] = *(const half8*)&A_lds[cur][(sidx) * 2560 + aoff + f * 256];      \
    __builtin_amdgcn_s_setprio(1);                                            \
    _Pragma("unroll")                                                         \
    for (int f = 0; f < 5; ++f) acc[f] = MFMAH32(A[f], Bc0, acc[f]);          \
    _Pragma("unroll")                                                         \
    for (int f = 0; f < 5; ++f) acc[f] = MFMAH32(A[f], Bc1, acc[f]);          \
    __builtin_amdgcn_s_setprio(0);                                            \
    Bc0 = Bd0; Bc1 = Bd1;                                                     \
    Bd0 = Bn0; Bd1 = Bn1;                                                     \
  }

  // prologue: stage chunk 0, prefetch bits chunk 1, preload B[g=0], B[g=1]
  br0 = *(const uint2*)&rowp0[0];
  br1 = *(const uint2*)&rowp1[0];
  STAGE(0)
  br0 = *(const uint2*)&rowp0[2];
  br1 = *(const uint2*)&rowp1[2];
  half8 Bc0, Bc1, Bd0, Bd1;
  {
    const ushort* bk = bp + lane * 8;
    Bc0 = *(const half8*)&bk[0];
    Bc1 = *(const half8*)&bk[512];
    const ushort* bd = bk + 1024;
    Bd0 = *(const half8*)&bd[0];
    Bd1 = *(const half8*)&bd[512];
  }
  __syncthreads();

  int aoff = kh * 5 * 256 + col * 8;   // wave's A-frag base within a j-pair

  for (int kc = 0; kc < 48; ++kc) {
    int cur = kc & 1;
    BURST(0)
    if (kc + 1 < 48) STAGE(cur ^ 1)                  // under s=0's shadow
    if (kc + 2 < 48) {                               // prefetch chunk kc+2
      br0 = *(const uint2*)&rowp0[(kc + 2) * 2];
      br1 = *(const uint2*)&rowp1[(kc + 2) * 2];
    }
    BURST(1)
    BURST(2)
    BURST(3)
    __syncthreads();
  }
#undef BURST
#undef STAGE

  // ---- fused LIF epilogue ----
  // C layout (verified m74/m101, r8-19): col=lane&31, row=(r&3)+8*(r>>2)+4*kh
  // local row lr = lb*10 + t (b-major);  h = acc * 2^-14 (exact unscale).
  float* h_lds = (float*)&A_lds[0][0];    // 160 rows x 64 cols f32 = 40 KB
  int lcol = wave * 32 + col;             // local col 0..127
#pragma unroll
  for (int ph = 0; ph < 2; ++ph) {
    __syncthreads();                      // LDS free / prev pass reads done
    if ((lcol >> 6) == ph) {
      int lc = lcol & 63;
#pragma unroll
      for (int f = 0; f < 5; ++f)
#pragma unroll
        for (int r = 0; r < 16; ++r) {
          int lr = f * 32 + (r & 3) + 8 * (r >> 2) + 4 * kh;
          h_lds[lr * 64 + lc] = acc[f][r] * SCALE_DN;
        }
    }
    __syncthreads();
    // scan: wave handles 4 b's; lanes = the 64 cols of this half
    int nbyte0 = xb * 16 + ph * 8;
#pragma unroll
    for (int i = 0; i < 4; ++i) {
      int lb = wave * 4 + i;
      int b = mb * 16 + lb;
      float v = 0.f;
#pragma unroll
      for (int t = 0; t < T_STEPS; ++t) {
        float h = h_lds[(lb * 10 + t) * 64 + lane];
        bool fire;
        {
#pragma clang fp contract(off)
          float vd = v * 0.3f;
          float vn = vd + h;
          fire = (vn >= 1.0f);
          v = fire ? 0.0f : vn;
        }
        unsigned long long mask = __ballot(fire);
        if (lane == 0)
          *(unsigned long long*)&spk[(size_t)t * (512*256) +
                                     (size_t)b * 256 + nbyte0] = mask;
      }
    }
  }
}

// ---------------- output layer, XCD-swizzled + B/aw pipelined, 2xf16 -------
__global__ __launch_bounds__(256) void out_mfma(
    const ushort* __restrict__ Ofrag,       // [32][64][2][512]
    const uint8_t* __restrict__ spk,        // [T][512][256]
    const float* __restrict__ bout,
    float* __restrict__ s) {                // [512][512], pre-zeroed
  int lin = blockIdx.x;
  int x = lin & 7;
  int r0 = lin >> 3;
  int y = r0 & 7;
  int t = r0 >> 3;
  int tid = threadIdx.x;
  int wave = tid >> 6, lane = tid & 63;
  int col  = lane & 15, kb = lane >> 4;
  int nt = x * 4 + wave;
  int m0 = y * 64;
  const ushort* bp = Ofrag + (size_t)nt * (64 * 1024);
  const uint8_t* st = spk + (size_t)t * (512*256);

  f32x4 acc[4] = {{0.f,0.f,0.f,0.f},{0.f,0.f,0.f,0.f},
                  {0.f,0.f,0.f,0.f},{0.f,0.f,0.f,0.f}};

  u32x4 aw[4], awn[4];
#pragma unroll
  for (int f = 0; f < 4; ++f)
    aw[f] = *(const u32x4*)&st[(size_t)(m0 + f*16 + col) * 256];
  half8 Bc0, Bc1;
  {
    const ushort* bk = bp + lane * 8;
    Bc0 = *(const half8*)&bk[0];
    Bc1 = *(const half8*)&bk[512];
  }

  for (int kc4 = 0; kc4 < 16; ++kc4) {      // K = 2048 = 16 * 4 * 32
    int nk4 = (kc4 + 1 < 16) ? kc4 + 1 : 15;
#pragma unroll
    for (int f = 0; f < 4; ++f)
      awn[f] = *(const u32x4*)&st[(size_t)(m0 + f*16 + col) * 256 + nk4*16];
#pragma unroll
    for (int sv = 0; sv < 4; ++sv) {
      int g1 = kc4 * 4 + sv + 1;
      if (g1 > 63) g1 = 63;
      const ushort* bn = bp + (size_t)g1 * 1024 + lane * 8;
      half8 Bn0 = *(const half8*)&bn[0];
      half8 Bn1 = *(const half8*)&bn[512];
      half8 A[4];
#pragma unroll
      for (int f = 0; f < 4; ++f)
        A[f] = expand8h((aw[f][sv] >> (kb*8)) & 0xFFu);
      __builtin_amdgcn_s_setprio(1);
#pragma unroll
      for (int f = 0; f < 4; ++f) acc[f] = MFMAH(A[f], Bc0, acc[f]);
#pragma unroll
      for (int f = 0; f < 4; ++f) acc[f] = MFMAH(A[f], Bc1, acc[f]);
      __builtin_amdgcn_s_setprio(0);
      Bc0 = Bn0; Bc1 = Bn1;
    }
#pragma unroll
    for (int f = 0; f < 4; ++f) aw[f] = awn[f];
  }
  float bo = bout[nt*16 + col];
#pragma unroll
  for (int f = 0; f < 4; ++f) {
#pragma unroll
    for (int r = 0; r < 4; ++r) {
      float out = acc[f][r] * SCALE_DN + bo;
      if (out > 0.0f) {
        int b = m0 + f*16 + kb*4 + r;
        atomicAdd(&s[(size_t)b * OUT_SZ + nt*16 + col], 1.0f);
      }
    }
  }
}

// ---------------------------------------------------------------------------
extern "C" void kernel_launch(void* const* d_in, const int* in_sizes, int n_in,
                              void* d_out, int out_size, void* d_ws, size_t ws_size,
                              hipStream_t stream) {
  const float* x    = (const float*)d_in[0];
  const float* Win  = (const float*)d_in[1];   // [2048][3072]
  const float* Wout = (const float*)d_in[2];   // [512][2048]
  const float* bout = (const float*)d_in[3];
  float* s = (float*)d_out;                    // [512][512]

  char* ws = (char*)d_ws;
  ushort*   Wfrag   = (ushort*)(ws + 0);           // 64*192*1024*2 = 25165824
  ushort*   Ofrag   = (ushort*)(ws + 25165824);    // 32*64*1024*2  = 4194304
  uint32_t* in_bits = (uint32_t*)(ws + 29360128);  // 5120*96*4     = 1966080
  uint8_t*  spk     = (uint8_t*)(ws + 31326208);   // 10*512*256    = 1310720

  Keys hk;
  for (int t = 0; t < T_STEPS; ++t) {
    uint32_t y0, y1;
    threefry2x32(0u, 42u, 0u, (uint32_t)t, y0, y1);
    hk.k[2*t] = y0; hk.k[2*t+1] = y1;
  }

  (void)hipMemsetAsync(d_out, 0, (size_t)OUT_SZ * B_SZ * sizeof(float), stream);
  hipLaunchKernelGGL(prep_kernel, dim3(3072 + 512 + NELEM/256), dim3(256), 0,
                     stream, x, Win, Wout, Wfrag, Ofrag, in_bits, hk);
  hipLaunchKernelGGL(gemm_hidden, dim3(512), dim3(256), 0, stream,
                     Wfrag, in_bits, spk);
  hipLaunchKernelGGL(out_mfma, dim3(8 * 8 * T_STEPS), dim3(256), 0, stream,
                     Ofrag, spk, bout, s);
}